// Round 14
// baseline (5179.631 us; speedup 1.0000x reference)
//
#include <hip/hip_runtime.h>
#include <hip/hip_bf16.h>
#include <hip/hip_fp16.h>

// StepWiseMLPAutoEncoder.
// Encoder is non-recurrent (scan carry = input column) -> big batched MFMA GEMMs.
// Decoder recurrence: persistent 67-WG kernel, weights pinned in LDS, r7-proven
// agent-atomic LLC transport. r14: NO global barrier -- wave-level DATAFLOW. Each wave
// polls only its 18 producers' gen-flags (9 parallel lines/iter, throttled), then loads
// its act slices and MFMAs; waves join at the LDS reduce. WAR safety via parity
// double-buffered act[2] (max skew 1 phase, opposite parity -- proven by flag algebra).
// y = a1 @ W2 deferred to one batched GEMM after the loop (r13 in-grid fusion was a wash).
// All internal math fp16 with fp32 MFMA accumulation (mfma_f32_16x16x32_f16).

typedef _Float16 f16x8 __attribute__((ext_vector_type(8)));
typedef float f32x4 __attribute__((ext_vector_type(4)));
typedef unsigned short u16;
typedef unsigned int u32;
typedef unsigned long long u64;

#define MFMA(a, b, c) __builtin_amdgcn_mfma_f32_16x16x32_f16((a), (b), (c), 0, 0, 0)

__device__ __forceinline__ float h2f(u16 u) { __half h; __builtin_memcpy(&h, &u, 2); return __half2float(h); }
__device__ __forceinline__ u16 f2h(float f) { __half h = __float2half(f); u16 u; __builtin_memcpy(&u, &h, 2); return u; }

// agent-scope (LLC) atomic transport helpers (r7-proven codegen path)
__device__ __forceinline__ void st_act4(u32* p, u32 v) {
  __hip_atomic_store(p, v, __ATOMIC_RELAXED, __HIP_MEMORY_SCOPE_AGENT);
}
__device__ __forceinline__ f16x8 ld_act16(const u16* p) {
  u64 lo = __hip_atomic_load((const u64*)p, __ATOMIC_RELAXED, __HIP_MEMORY_SCOPE_AGENT);
  u64 hi = __hip_atomic_load((const u64*)(p + 4), __ATOMIC_RELAXED, __HIP_MEMORY_SCOPE_AGENT);
  union { u64 q[2]; f16x8 v; } u;
  u.q[0] = lo; u.q[1] = hi;
  return u.v;
}

// ---------------- fused prep ----------------
__device__ __forceinline__ void pack_body(const float* __restrict__ W, int ldw, int row0,
                                          int Kr, int Nr, u16* __restrict__ out, int Np,
                                          int id, int total) {
  if (id >= total) return;
  int kq = id / Np, n = id % Np;
  union { u16 v[8]; uint4 q; } un;
#pragma unroll
  for (int j = 0; j < 8; ++j) {
    int k = kq * 8 + j;
    float f = (k < Kr && n < Nr) ? W[(size_t)(row0 + k) * ldw + n] : 0.f;
    un.v[j] = f2h(f);
  }
  *(uint4*)(out + (size_t)id * 8) = un.q;
}

__global__ __launch_bounds__(256) void prep_kernel(
    const float* __restrict__ ew0, const float* __restrict__ ew1, const float* __restrict__ ew2,
    const float* __restrict__ dw0, const float* __restrict__ dw1, const float* __restrict__ dw2,
    const float* __restrict__ db2,
    u16* We0p, u16* We1p, u16* We2p, u16* Wh0p, u16* Wd0p, u16* Wd1p, u16* Wd2p,
    u16* xT, float* c2x, int* flags, u16* acts) {
  const int b = blockIdx.x, tid = threadIdx.x;
  if (b < 1408) {
    pack_body(ew0, 1387, 0, 2048, 1387, We0p, 1408, b * 256 + tid, 256 * 1408);
  } else if (b < 1936) {
    pack_body(ew1, 726, 0, 1387, 726, We1p, 768, (b - 1408) * 256 + tid, 176 * 768);
  } else if (b < 1960) {
    pack_body(ew2, 64, 0, 726, 64, We2p, 64, (b - 1936) * 256 + tid, 96 * 64);
  } else if (b < 1996) {
    pack_body(dw0, 1067, 0, 64, 1067, Wh0p, 1152, (b - 1960) * 256 + tid, 8 * 1152);
  } else if (b < 2644) {
    pack_body(dw0, 1067, 64, 1024, 1067, Wd0p, 1152, (b - 1996) * 256 + tid, 144 * 1152);
  } else if (b < 3292) {
    pack_body(dw1, 1046, 0, 1067, 1046, Wd1p, 1152, (b - 2644) * 256 + tid, 144 * 1152);
  } else if (b < 3940) {
    pack_body(dw2, 1024, 0, 1046, 1024, Wd2p, 1152, (b - 3292) * 256 + tid, 144 * 1152);
  } else if (b < 4068) {
    int i = (b - 3940) * 256 + tid;           // zero xT t=-1 rows (32*1024)
    if (i < 32768) xT[i] = 0;
  } else if (b < 4073) {
    int n = (b - 4068) * 256 + tid;           // c2x = db2 @ dw0[64:1088]
    if (n < 1152) {
      float s = 0.f;
      if (n < 1067) {
        for (int k = 0; k < 1024; ++k) s += db2[k] * dw0[(size_t)(64 + k) * 1067 + n];
      }
      c2x[n] = s;
    }
  } else if (b < 4082) {
    int i = (b - 4073) * 256 + tid;           // zero flags (67*32 ints = 2144)
    if (i < 2144) flags[i] = 0;
  } else {
    int i = (b - 4082) * 256 + tid;           // zero act parity buffers (2*36864 u16)
    if (i < 9216) { uint4 z = {}; *(uint4*)(acts + (size_t)i * 8) = z; }
  }
}

// ---------------- transpose x -> xT ----------------
__global__ __launch_bounds__(256) void transpose_kernel(const float* __restrict__ x, u16* __restrict__ xT) {
  __shared__ float tile[64][65];
  int b = blockIdx.z, f0 = blockIdx.x * 64, t0 = blockIdx.y * 64;
  const float* xp = x + (size_t)b * (1024 * 512);
  for (int rep = 0; rep < 16; ++rep) {
    int e = rep * 256 + threadIdx.x;
    int fi = e >> 6, tj = e & 63;
    tile[fi][tj] = xp[(size_t)(f0 + fi) * 512 + t0 + tj];
  }
  __syncthreads();
  for (int rep = 0; rep < 16; ++rep) {
    int e = rep * 256 + threadIdx.x;
    int tj = e >> 6, fi = e & 63;
    xT[(size_t)((t0 + tj + 1) * 32 + b) * 1024 + f0 + fi] = f2h(tile[fi][tj]);
  }
}

// ---------------- dw2 -> f16 [1152][1024] (A16 aliases act2: must run after hid GEMM) ----
__global__ __launch_bounds__(256) void cvt_a_kernel(const float* __restrict__ src, u16* __restrict__ dst) {
  int i = blockIdx.x * 256 + threadIdx.x;
  int r = i >> 10;
  dst[i] = f2h(r < 1046 ? src[i] : 0.f);
}

// ---------------- generic GEMM (unchanged, proven) ----------------
template <int TWOSRC, int ACT, int T1, int T2, int PACKO>
__global__ __launch_bounds__(256) void gemm_kernel(
    const u16* __restrict__ A, int lda,
    const u16* __restrict__ Wp, int Np,
    const float* __restrict__ bias, int nb,
    const float* __restrict__ wt1, int nw1,
    const float* __restrict__ wt2, int nw2,
    u16* __restrict__ out, int ldo, int Kp) {
  __shared__ u16 As[128][72];
  __shared__ u16 Bs[8 * 64 * 8];
  const int tid = threadIdx.x;
  const int bx = blockIdx.x, by = blockIdx.y;
  const int m0 = by * 128, n0 = bx * 64;
  const int l = tid & 63, wv = tid >> 6, lm = l & 15, lg = l >> 4;
  f32x4 acc[2][4] = {};
  for (int k0 = 0; k0 < Kp; k0 += 64) {
#pragma unroll
    for (int c = 0; c < 4; ++c) {
      int idx = c * 256 + tid;
      int row = idx >> 3, seg = idx & 7;
      int kk = k0 + seg * 8;
      const u16* ap;
      if (TWOSRC) {
        int half = (kk >= 1024) ? 1 : 0;
        ap = A + (size_t)(m0 + row + half * 32) * lda + (kk - half * 1024);
      } else {
        ap = A + (size_t)(m0 + row) * lda + kk;
      }
      *(uint4*)&As[row][seg * 8] = *(const uint4*)ap;
    }
#pragma unroll
    for (int c = 0; c < 2; ++c) {
      int idx = c * 256 + tid;
      int e0 = idx * 8;
      int kq = e0 >> 9, inner = e0 & 511;
      const u16* gp = Wp + (size_t)((k0 >> 3) + kq) * (Np * 8) + n0 * 8 + inner;
      *(uint4*)(Bs + e0) = *(const uint4*)gp;
    }
    __syncthreads();
#pragma unroll
    for (int ks = 0; ks < 2; ++ks) {
      f16x8 af0 = *(const f16x8*)&As[wv * 32 + lm][ks * 32 + lg * 8];
      f16x8 af1 = *(const f16x8*)&As[wv * 32 + 16 + lm][ks * 32 + lg * 8];
#pragma unroll
      for (int nf = 0; nf < 4; ++nf) {
        f16x8 bfr = *(const f16x8*)(Bs + ((ks * 4 + lg) * 64 + nf * 16 + lm) * 8);
        acc[0][nf] = MFMA(af0, bfr, acc[0][nf]);
        acc[1][nf] = MFMA(af1, bfr, acc[1][nf]);
      }
    }
    __syncthreads();
  }
#pragma unroll
  for (int mr = 0; mr < 2; ++mr) {
    int rb = m0 + wv * 32 + mr * 16;
    int tt = rb >> 5;
#pragma unroll
    for (int nf = 0; nf < 4; ++nf) {
      int col = n0 + nf * 16 + lm;
      float bv = (col < nb) ? bias[col] : 0.f;
      if (T1) bv += (float)tt * (1.f / 512.f) * ((col < nw1) ? wt1[col] : 0.f);
      if (T2) bv += ((tt > 0) ? 1.f : 0.f) * ((col < nw2) ? wt2[col] : 0.f);
#pragma unroll
      for (int v = 0; v < 4; ++v) {
        float xv = acc[mr][nf][v] + bv;
        if (ACT == 1) xv = fmaxf(xv, 0.f);
        if (ACT == 2) xv = tanhf(xv);
        if (PACKO) {
          int r = rb + lg * 4 + v;
          out[((size_t)(r >> 3) * Np + col) * 8 + (r & 7)] = f2h(xv);
        } else {
          out[(size_t)(rb + lg * 4 + v) * ldo + col] = f2h(xv);
        }
      }
    }
  }
}

// ---------------- persistent decoder: wave-level dataflow ----------------
#define NWG 67

// dataflow matvec: each wave waits only ITS producers (kq/2 for its 36 kq slices;
// 18 distinct flag lines, polled 9-parallel per iter, throttled), then loads + MFMAs.
// Join across waves at the LDS reduce. red[] WAR-safe: phase g+1 red-writes happen after
// syncthreads(B) of phase g (all red reads done).
__device__ __forceinline__ void dec_mm_df(const u16* __restrict__ in, const u16* wl,
                                          const int* flags, int gen_in,
                                          float (*red)[512], int lm, int lg, int wv,
                                          int e0, float& s0, float& s1) {
  const int kq0 = wv * 36;
  // wait for my 18 producers (9 flag loads per iteration, independent -> overlapped)
  for (;;) {
    int mn = 0x7fffffff;
#pragma unroll
    for (int ks = 0; ks < 9; ++ks) {
      int prod = (kq0 + ks * 4 + lg) >> 1;
      if (prod < NWG) {
        int f = __hip_atomic_load(flags + prod * 32, __ATOMIC_RELAXED, __HIP_MEMORY_SCOPE_AGENT);
        mn = f < mn ? f : mn;
      }
    }
    if (mn >= gen_in) break;
    __builtin_amdgcn_s_sleep(1);                 // throttle (r10: unthrottled congests LLC)
  }
  asm volatile("" ::: "memory");                  // no act-load hoisting above the wait
  f16x8 av0[9], av1[9];
#pragma unroll
  for (int ks = 0; ks < 9; ++ks) {
    int kq = kq0 + ks * 4 + lg;
    const u16* pa = in + kq * 256 + lm * 8;
    av0[ks] = ld_act16(pa);
    av1[ks] = ld_act16(pa + 128);
  }
  f32x4 acc0 = {}, acc1 = {};
#pragma unroll
  for (int ks = 0; ks < 9; ++ks) {
    int kq = kq0 + ks * 4 + lg;
    f16x8 bf = *(const f16x8*)(wl + ((size_t)kq * 16 + lm) * 8);
    acc0 = MFMA(av0[ks], bf, acc0);
    acc1 = MFMA(av1[ks], bf, acc1);
  }
#pragma unroll
  for (int v = 0; v < 4; ++v) {
    red[wv][(lg * 4 + v) * 16 + lm] = acc0[v];
    red[wv][(16 + lg * 4 + v) * 16 + lm] = acc1[v];
  }
  __syncthreads();   // join A (4 waves)
  s0 = red[0][e0] + red[1][e0] + red[2][e0] + red[3][e0];
  s1 = red[0][e0 + 1] + red[1][e0 + 1] + red[2][e0 + 1] + red[3][e0 + 1];
}

__global__ __launch_bounds__(256, 1) void decoder_kernel(
    const u16* __restrict__ W1p, const u16* __restrict__ Mp,
    const u16* __restrict__ hpart, const float* __restrict__ db1,
    u16* actp0, u16* actp1, u16* __restrict__ a1buf, int* flags) {
  __shared__ __align__(16) u16 wlds[2 * 2304 * 8];  // 73,728 B: [W1|M] slices
  __shared__ float red[4][512];                      // 8,192 B
  const int tid = threadIdx.x, bid = blockIdx.x;
  const int l = tid & 63, wv = tid >> 6, lm = l & 15, lg = l >> 4;
  const int n0 = bid * 16;
  for (int i = tid; i < 2 * 2304; i += 256) {
    int layer = i / 2304, rem = i % 2304, kq = rem >> 4, c = rem & 15;
    const u16* base = (layer == 0) ? W1p : Mp;
    *(uint4*)(wlds + (size_t)i * 8) = *(const uint4*)(base + ((size_t)kq * 1152 + n0 + c) * 8);
  }
  const int e0 = tid * 2, row = e0 >> 4, c0 = e0 & 15, na = n0 + c0;
  const size_t slotoff = ((size_t)(na >> 3) * 32 + row) * 8 + (na & 7);
  u32* slot0 = (u32*)(actp0 + slotoff);   // parity 0 (even gen outputs)
  u32* slot1 = (u32*)(actp1 + slotoff);   // parity 1 (prologue + odd gen outputs)
  const float bv0 = (na < 1046) ? db1[na] : 0.f;
  const float bv1 = (na + 1 < 1046) ? db1[na + 1] : 0.f;
  int* myflag = flags + bid * 32;
  // prologue (gen 1, parity 1): a0(0) = relu(hpart[0])   (a1(-1)=0 so M-term vanishes)
  {
    u32 pk = *(const u32*)(hpart + row * 1152 + na);
    float s0 = fmaxf(h2f((u16)(pk & 0xffff)), 0.f);
    float s1 = fmaxf(h2f((u16)(pk >> 16)), 0.f);
    st_act4(slot1, (u32)f2h(s0) | ((u32)f2h(s1) << 16));
  }
  asm volatile("s_waitcnt vmcnt(0)" ::: "memory");
  __syncthreads();   // weights staged + prologue stores drained by all waves
  if (tid == 0) __hip_atomic_store(myflag, 1, __ATOMIC_RELAXED, __HIP_MEMORY_SCOPE_AGENT);
  int gen = 1;
#pragma unroll 1
  for (int t = 0; t < 512; ++t) {
    // hpart prefetch first (in-order vmcnt retire -> free; consumed in phase 2)
    u32 hpk = 0;
    if (t < 511) hpk = *(const u32*)(hpart + (size_t)(t + 1) * 36864 + row * 1152 + na);
    // ---- phase 1 (gen_out = 2t+2): a1 = relu(a0 @ W1 + db1); in parity 1, out parity 0 ----
    float s0, s1;
    dec_mm_df(actp1, wlds, flags, gen, red, lm, lg, wv, e0, s0, s1);
    s0 = fmaxf(s0 + bv0, 0.f);
    s1 = fmaxf(s1 + bv1, 0.f);
    u32 opk = (u32)f2h(s0) | ((u32)f2h(s1) << 16);
    *(u32*)(a1buf + ((size_t)(t * 32 + row) * 1088 + na)) = opk;   // y-GEMM log
    if (t == 511) break;   // no consumer for the last phase-1 output
    st_act4(slot0, opk);
    asm volatile("s_waitcnt vmcnt(0)" ::: "memory");
    __syncthreads();   // B: red reads done + my stores drained
    ++gen;             // = 2t+2
    if (tid == 0) __hip_atomic_store(myflag, gen, __ATOMIC_RELAXED, __HIP_MEMORY_SCOPE_AGENT);
    // ---- phase 2 (gen_out = 2t+3): a0' = relu(a1 @ M + hpart[t+1]); in par 0, out par 1 ----
    dec_mm_df(actp0, wlds + 2304 * 8, flags, gen, red, lm, lg, wv, e0, s0, s1);
    s0 = fmaxf(s0 + h2f((u16)(hpk & 0xffff)), 0.f);
    s1 = fmaxf(s1 + h2f((u16)(hpk >> 16)), 0.f);
    st_act4(slot1, (u32)f2h(s0) | ((u32)f2h(s1) << 16));
    asm volatile("s_waitcnt vmcnt(0)" ::: "memory");
    __syncthreads();   // B
    ++gen;             // = 2t+3
    if (tid == 0) __hip_atomic_store(myflag, gen, __ATOMIC_RELAXED, __HIP_MEMORY_SCOPE_AGENT);
  }
}

// ---------------- finalize: dout[b][n][t] = ytmp[t*32+b][n] ----------------
__global__ __launch_bounds__(256) void finalize_kernel(const u16* __restrict__ ytmp,
                                                       float* __restrict__ dout) {
  __shared__ float tile[64][65];
  int b = blockIdx.z, n0 = blockIdx.x * 64, t0 = blockIdx.y * 64;
  for (int rep = 0; rep < 16; ++rep) {
    int e = rep * 256 + threadIdx.x;
    int tt = e >> 6, nn = e & 63;
    tile[tt][nn] = h2f(ytmp[(size_t)((t0 + tt) * 32 + b) * 1024 + n0 + nn]);
  }
  __syncthreads();
  for (int rep = 0; rep < 16; ++rep) {
    int e = rep * 256 + threadIdx.x;
    int nn = e >> 6, tt = e & 63;
    dout[((size_t)b * 1024 + n0 + nn) * 512 + t0 + tt] = tile[tt][nn];
  }
}

// ---------------- launch ----------------
extern "C" void kernel_launch(void* const* d_in, const int* in_sizes, int n_in,
                              void* d_out, int out_size, void* d_ws, size_t ws_size,
                              hipStream_t stream) {
  (void)in_sizes; (void)n_in; (void)out_size; (void)ws_size;
  const float* x   = (const float*)d_in[0];
  const float* ew0 = (const float*)d_in[1];
  const float* eb0 = (const float*)d_in[2];
  const float* ew1 = (const float*)d_in[3];
  const float* eb1 = (const float*)d_in[4];
  const float* ew2 = (const float*)d_in[5];
  const float* eb2 = (const float*)d_in[6];
  const float* dw0 = (const float*)d_in[7];
  const float* db0 = (const float*)d_in[8];
  const float* dw1 = (const float*)d_in[9];
  const float* db1 = (const float*)d_in[10];
  const float* dw2 = (const float*)d_in[11];
  const float* db2 = (const float*)d_in[12];

  char* ws = (char*)d_ws;
  u16* xT    = (u16*)(ws + 0);                      // 33.6MB; dead after encoder L0 -> reused as ytmp
  u16* ytmp  = (u16*)(ws + 0);
  u16* act2  = (u16*)(ws + 33619968ull);            // 25MB region (dead after hid GEMM):
  u16* A16   = (u16*)(ws + 33619968ull);            //   dw2 f16 [1152][1024] (aliases act2)
  u16* Mp    = (u16*)(ws + 33619968ull + 2359296ull);   // packed M (written after act2 dead)
  u16* hid   = (u16*)(ws + 58785792ull);
  u16* hpart = (u16*)(ws + 60882944ull);            // 16384*1152
  u16* We0p  = (u16*)(ws + 98631680ull);
  u16* We1p  = (u16*)(ws + 104398848ull);
  u16* We2p  = (u16*)(ws + 106561536ull);
  u16* Wh0p  = (u16*)(ws + 106659840ull);
  u16* Wd0p  = (u16*)(ws + 106807296ull);
  u16* Wd1p  = (u16*)(ws + 109461504ull);
  u16* Wd2p  = (u16*)(ws + 112115712ull);
  float* c2x = (float*)(ws + 114769920ull);
  u16* actp0 = (u16*)(ws + 114774528ull);           // parity-0 acts [144][32][8]
  u16* actp1 = (u16*)(ws + 114848256ull);           // parity-1 acts
  int* flags = (int*)(ws + 114921984ull);           // 67*32 ints (never aliased)

  u16* act1  = (u16*)d_out;   // staged in d_out; dead after encoder L1
  u16* a1buf = (u16*)d_out;   // [16384][1088] f16 a1-log (cols>=1067 multiply zero W rows)
  float* dout = (float*)d_out;

  // fused prep: weight packs, xT t=-1 zero, c2x, flag zero, act zero (one launch)
  prep_kernel<<<dim3(4118), dim3(256), 0, stream>>>(
      ew0, ew1, ew2, dw0, dw1, dw2, db2,
      We0p, We1p, We2p, Wh0p, Wd0p, Wd1p, Wd2p, xT, c2x, flags, actp0);

  transpose_kernel<<<dim3(16, 8, 32), dim3(256), 0, stream>>>(x, xT);

  // encoder
  gemm_kernel<1, 1, 1, 0, 0><<<dim3(22, 128), dim3(256), 0, stream>>>(
      xT, 1024, We0p, 1408, eb0, 1387, ew0 + (size_t)2048 * 1387, 1387, nullptr, 0, act1, 1408, 2048);
  gemm_kernel<0, 1, 0, 0, 0><<<dim3(12, 128), dim3(256), 0, stream>>>(
      act1, 1408, We1p, 768, eb1, 726, nullptr, 0, nullptr, 0, act2, 768, 1408);
  gemm_kernel<0, 2, 0, 0, 0><<<dim3(1, 128), dim3(256), 0, stream>>>(
      act2, 768, We2p, 64, eb2, 64, nullptr, 0, nullptr, 0, hid, 64, 768);
  gemm_kernel<0, 0, 1, 1, 0><<<dim3(18, 128), dim3(256), 0, stream>>>(
      hid, 64, Wh0p, 1152, db0, 1067, dw0 + (size_t)1088 * 1067, 1067, c2x, 1152, hpart, 1152, 64);

  // M = dw2 @ dw0[64:1088]  (act2 region dead after the hid gemm; A16/Mp live there)
  cvt_a_kernel<<<dim3(4608), dim3(256), 0, stream>>>(dw2, A16);
  gemm_kernel<0, 0, 0, 0, 1><<<dim3(18, 9), dim3(256), 0, stream>>>(
      A16, 1024, Wd0p, 1152, nullptr, 0, nullptr, 0, nullptr, 0, Mp, 0, 1024);

  // sequential recurrence (wave-dataflow; a1-log written to a1buf in d_out)
  decoder_kernel<<<dim3(NWG), dim3(256), 0, stream>>>(Wd1p, Mp, hpart, db1, actp0, actp1, a1buf, flags);

  // deferred y = a1 @ W2 + db2  (batched over all t), then transpose into d_out
  gemm_kernel<0, 0, 0, 0, 0><<<dim3(16, 128), dim3(256), 0, stream>>>(
      a1buf, 1088, Wd2p, 1152, db2, 1024, nullptr, 0, nullptr, 0, ytmp, 1024, 1088);
  finalize_kernel<<<dim3(16, 8, 32), dim3(256), 0, stream>>>(ytmp, dout);
}

// Round 15
// 3589.938 us; speedup vs baseline: 1.4428x; 1.4428x over previous
//
#include <hip/hip_runtime.h>
#include <hip/hip_bf16.h>
#include <hip/hip_fp16.h>

// StepWiseMLPAutoEncoder.
// Encoder is non-recurrent (scan carry = input column) -> big batched MFMA GEMMs
// (r15: 128x128 tiles for the three large GEMMs -- 1.5x FLOP/staged-byte).
// Decoder recurrence: persistent 67-WG kernel, weights pinned in LDS, r7/r12-PROVEN
// agent-atomic LLC transport + throttled single-flag barrier (protocol search closed:
// r8/r9/r10/r13/r14 alternatives all regressed). a1buf log after the barrier (r12).
// y = a1 @ W2 deferred to one batched GEMM. Internal math fp16, fp32 MFMA accumulation.

typedef _Float16 f16x8 __attribute__((ext_vector_type(8)));
typedef float f32x4 __attribute__((ext_vector_type(4)));
typedef unsigned short u16;
typedef unsigned int u32;
typedef unsigned long long u64;

#define MFMA(a, b, c) __builtin_amdgcn_mfma_f32_16x16x32_f16((a), (b), (c), 0, 0, 0)

__device__ __forceinline__ float h2f(u16 u) { __half h; __builtin_memcpy(&h, &u, 2); return __half2float(h); }
__device__ __forceinline__ u16 f2h(float f) { __half h = __float2half(f); u16 u; __builtin_memcpy(&u, &h, 2); return u; }

// agent-scope (LLC) atomic transport helpers (r7-proven codegen path)
__device__ __forceinline__ void st_act4(u32* p, u32 v) {
  __hip_atomic_store(p, v, __ATOMIC_RELAXED, __HIP_MEMORY_SCOPE_AGENT);
}
__device__ __forceinline__ f16x8 ld_act16(const u16* p) {
  u64 lo = __hip_atomic_load((const u64*)p, __ATOMIC_RELAXED, __HIP_MEMORY_SCOPE_AGENT);
  u64 hi = __hip_atomic_load((const u64*)(p + 4), __ATOMIC_RELAXED, __HIP_MEMORY_SCOPE_AGENT);
  union { u64 q[2]; f16x8 v; } u;
  u.q[0] = lo; u.q[1] = hi;
  return u.v;
}

// ---------------- fused prep ----------------
__device__ __forceinline__ void pack_body(const float* __restrict__ W, int ldw, int row0,
                                          int Kr, int Nr, u16* __restrict__ out, int Np,
                                          int id, int total) {
  if (id >= total) return;
  int kq = id / Np, n = id % Np;
  union { u16 v[8]; uint4 q; } un;
#pragma unroll
  for (int j = 0; j < 8; ++j) {
    int k = kq * 8 + j;
    float f = (k < Kr && n < Nr) ? W[(size_t)(row0 + k) * ldw + n] : 0.f;
    un.v[j] = f2h(f);
  }
  *(uint4*)(out + (size_t)id * 8) = un.q;
}

__global__ __launch_bounds__(256) void prep_kernel(
    const float* __restrict__ ew0, const float* __restrict__ ew1, const float* __restrict__ ew2,
    const float* __restrict__ dw0, const float* __restrict__ dw1, const float* __restrict__ dw2,
    const float* __restrict__ db2,
    u16* We0p, u16* We1p, u16* We2p, u16* Wh0p, u16* Wd0p, u16* Wd1p, u16* Wd2p,
    u16* xT, float* c2x, int* flags, u16* acts) {
  const int b = blockIdx.x, tid = threadIdx.x;
  if (b < 1408) {
    pack_body(ew0, 1387, 0, 2048, 1387, We0p, 1408, b * 256 + tid, 256 * 1408);
  } else if (b < 1936) {
    pack_body(ew1, 726, 0, 1387, 726, We1p, 768, (b - 1408) * 256 + tid, 176 * 768);
  } else if (b < 1960) {
    pack_body(ew2, 64, 0, 726, 64, We2p, 64, (b - 1936) * 256 + tid, 96 * 64);
  } else if (b < 1996) {
    pack_body(dw0, 1067, 0, 64, 1067, Wh0p, 1152, (b - 1960) * 256 + tid, 8 * 1152);
  } else if (b < 2644) {
    pack_body(dw0, 1067, 64, 1024, 1067, Wd0p, 1152, (b - 1996) * 256 + tid, 144 * 1152);
  } else if (b < 3292) {
    pack_body(dw1, 1046, 0, 1067, 1046, Wd1p, 1152, (b - 2644) * 256 + tid, 144 * 1152);
  } else if (b < 3940) {
    pack_body(dw2, 1024, 0, 1046, 1024, Wd2p, 1152, (b - 3292) * 256 + tid, 144 * 1152);
  } else if (b < 4068) {
    int i = (b - 3940) * 256 + tid;           // zero xT t=-1 rows (32*1024)
    if (i < 32768) xT[i] = 0;
  } else if (b < 4073) {
    int n = (b - 4068) * 256 + tid;           // c2x = db2 @ dw0[64:1088]
    if (n < 1152) {
      float s = 0.f;
      if (n < 1067) {
        for (int k = 0; k < 1024; ++k) s += db2[k] * dw0[(size_t)(64 + k) * 1067 + n];
      }
      c2x[n] = s;
    }
  } else if (b < 4082) {
    int i = (b - 4073) * 256 + tid;           // zero flags (67*32 ints = 2144)
    if (i < 2144) flags[i] = 0;
  } else {
    int i = (b - 4082) * 256 + tid;           // zero a0/a1 acts (2*36864 u16 = 9216 uint4)
    if (i < 9216) { uint4 z = {}; *(uint4*)(acts + (size_t)i * 8) = z; }
  }
}

// ---------------- transpose x -> xT ----------------
__global__ __launch_bounds__(256) void transpose_kernel(const float* __restrict__ x, u16* __restrict__ xT) {
  __shared__ float tile[64][65];
  int b = blockIdx.z, f0 = blockIdx.x * 64, t0 = blockIdx.y * 64;
  const float* xp = x + (size_t)b * (1024 * 512);
  for (int rep = 0; rep < 16; ++rep) {
    int e = rep * 256 + threadIdx.x;
    int fi = e >> 6, tj = e & 63;
    tile[fi][tj] = xp[(size_t)(f0 + fi) * 512 + t0 + tj];
  }
  __syncthreads();
  for (int rep = 0; rep < 16; ++rep) {
    int e = rep * 256 + threadIdx.x;
    int tj = e >> 6, fi = e & 63;
    xT[(size_t)((t0 + tj + 1) * 32 + b) * 1024 + f0 + fi] = f2h(tile[fi][tj]);
  }
}

// ---------------- dw2 -> f16 [1152][1024] (A16 aliases act2: must run after hid GEMM) ----
__global__ __launch_bounds__(256) void cvt_a_kernel(const float* __restrict__ src, u16* __restrict__ dst) {
  int i = blockIdx.x * 256 + threadIdx.x;
  int r = i >> 10;
  dst[i] = f2h(r < 1046 ? src[i] : 0.f);
}

// ---------------- generic GEMM (proven; r15: BN templated, 64 or 128) ----------------
template <int TWOSRC, int ACT, int T1, int T2, int PACKO, int BN>
__global__ __launch_bounds__(256) void gemm_kernel(
    const u16* __restrict__ A, int lda,
    const u16* __restrict__ Wp, int Np,
    const float* __restrict__ bias, int nb,
    const float* __restrict__ wt1, int nw1,
    const float* __restrict__ wt2, int nw2,
    u16* __restrict__ out, int ldo, int Kp) {
  __shared__ u16 As[128][72];
  __shared__ u16 Bs[8 * BN * 8];
  const int tid = threadIdx.x;
  const int bx = blockIdx.x, by = blockIdx.y;
  const int m0 = by * 128, n0 = bx * BN;
  const int l = tid & 63, wv = tid >> 6, lm = l & 15, lg = l >> 4;
  f32x4 acc[2][BN / 16] = {};
  for (int k0 = 0; k0 < Kp; k0 += 64) {
#pragma unroll
    for (int c = 0; c < 4; ++c) {
      int idx = c * 256 + tid;
      int row = idx >> 3, seg = idx & 7;
      int kk = k0 + seg * 8;
      const u16* ap;
      if (TWOSRC) {
        int half = (kk >= 1024) ? 1 : 0;
        ap = A + (size_t)(m0 + row + half * 32) * lda + (kk - half * 1024);
      } else {
        ap = A + (size_t)(m0 + row) * lda + kk;
      }
      *(uint4*)&As[row][seg * 8] = *(const uint4*)ap;
    }
#pragma unroll
    for (int c = 0; c < BN / 32; ++c) {
      int idx = c * 256 + tid;
      int e0 = idx * 8;
      int kq = e0 / (BN * 8), inner = e0 % (BN * 8);
      const u16* gp = Wp + (size_t)((k0 >> 3) + kq) * (Np * 8) + n0 * 8 + inner;
      *(uint4*)(Bs + e0) = *(const uint4*)gp;
    }
    __syncthreads();
#pragma unroll
    for (int ks = 0; ks < 2; ++ks) {
      f16x8 af0 = *(const f16x8*)&As[wv * 32 + lm][ks * 32 + lg * 8];
      f16x8 af1 = *(const f16x8*)&As[wv * 32 + 16 + lm][ks * 32 + lg * 8];
#pragma unroll
      for (int nf = 0; nf < BN / 16; ++nf) {
        f16x8 bfr = *(const f16x8*)(Bs + ((ks * 4 + lg) * BN + nf * 16 + lm) * 8);
        acc[0][nf] = MFMA(af0, bfr, acc[0][nf]);
        acc[1][nf] = MFMA(af1, bfr, acc[1][nf]);
      }
    }
    __syncthreads();
  }
#pragma unroll
  for (int mr = 0; mr < 2; ++mr) {
    int rb = m0 + wv * 32 + mr * 16;
    int tt = rb >> 5;
#pragma unroll
    for (int nf = 0; nf < BN / 16; ++nf) {
      int col = n0 + nf * 16 + lm;
      float bv = (col < nb) ? bias[col] : 0.f;
      if (T1) bv += (float)tt * (1.f / 512.f) * ((col < nw1) ? wt1[col] : 0.f);
      if (T2) bv += ((tt > 0) ? 1.f : 0.f) * ((col < nw2) ? wt2[col] : 0.f);
#pragma unroll
      for (int v = 0; v < 4; ++v) {
        float xv = acc[mr][nf][v] + bv;
        if (ACT == 1) xv = fmaxf(xv, 0.f);
        if (ACT == 2) xv = tanhf(xv);
        if (PACKO) {
          int r = rb + lg * 4 + v;
          out[((size_t)(r >> 3) * Np + col) * 8 + (r & 7)] = f2h(xv);
        } else {
          out[(size_t)(rb + lg * 4 + v) * ldo + col] = f2h(xv);
        }
      }
    }
  }
}

// ---------------- persistent decoder (r12-proven, byte-identical) ----------------
#define NWG 67

// r7-PROVEN barrier: drain, syncthreads, tid0 flag, throttled 67-lane poll, syncthreads.
__device__ __forceinline__ void gbar(int* flags, int bid, int tid, int gen) {
  asm volatile("s_waitcnt vmcnt(0)" ::: "memory");   // act stores acked at LLC
  __syncthreads();
  if (tid == 0)
    __hip_atomic_store(flags + bid * 32, gen, __ATOMIC_RELAXED, __HIP_MEMORY_SCOPE_AGENT);
  if (tid < NWG) {
    while (__hip_atomic_load(flags + tid * 32, __ATOMIC_RELAXED, __HIP_MEMORY_SCOPE_AGENT) < gen)
      __builtin_amdgcn_s_sleep(1);                   // throttle: unthrottled poll congests LLC (r10)
  }
  __syncthreads();
}

// s = (in[32][K-packed] @ Wlds)[thread's 2 cols]; acts packed [kq][32][8]; 4-wave K-split.
__device__ __forceinline__ void dec_mm(const u16* __restrict__ in, const u16* wl,
                                       float (*red)[512], int tid, int lm, int lg, int wv,
                                       int e0, float& s0, float& s1) {
  const int kq0 = wv * 36;
  f32x4 acc0 = {}, acc1 = {};
#pragma unroll
  for (int ks = 0; ks < 9; ++ks) {
    int kq = kq0 + ks * 4 + lg;
    const u16* pa = in + kq * 256 + lm * 8;
    f16x8 a0f = ld_act16(pa);
    f16x8 a1f = ld_act16(pa + 128);
    f16x8 bf = *(const f16x8*)(wl + ((size_t)kq * 16 + lm) * 8);
    acc0 = MFMA(a0f, bf, acc0);
    acc1 = MFMA(a1f, bf, acc1);
  }
#pragma unroll
  for (int v = 0; v < 4; ++v) {
    red[wv][(lg * 4 + v) * 16 + lm] = acc0[v];
    red[wv][(16 + lg * 4 + v) * 16 + lm] = acc1[v];
  }
  __syncthreads();
  s0 = red[0][e0] + red[1][e0] + red[2][e0] + red[3][e0];
  s1 = red[0][e0 + 1] + red[1][e0 + 1] + red[2][e0 + 1] + red[3][e0 + 1];
}

__global__ __launch_bounds__(256, 1) void decoder_kernel(
    const u16* __restrict__ W1p, const u16* __restrict__ Mp,
    const u16* __restrict__ hpart, const float* __restrict__ db1,
    u16* a0, u16* a1, u16* __restrict__ a1buf, int* flags) {
  __shared__ __align__(16) u16 wlds[2 * 2304 * 8];  // 73,728 B: [W1|M] slices
  __shared__ float red[4][512];                      // 8,192 B
  const int tid = threadIdx.x, bid = blockIdx.x;
  const int l = tid & 63, wv = tid >> 6, lm = l & 15, lg = l >> 4;
  const int n0 = bid * 16;
  for (int i = tid; i < 2 * 2304; i += 256) {
    int layer = i / 2304, rem = i % 2304, kq = rem >> 4, c = rem & 15;
    const u16* base = (layer == 0) ? W1p : Mp;
    *(uint4*)(wlds + (size_t)i * 8) = *(const uint4*)(base + ((size_t)kq * 1152 + n0 + c) * 8);
  }
  const int e0 = tid * 2, row = e0 >> 4, c0 = e0 & 15, na = n0 + c0;
  u32* a0slot = (u32*)(a0 + (((size_t)(na >> 3) * 32 + row) * 8 + (na & 7)));
  u32* a1slot = (u32*)(a1 + (((size_t)(na >> 3) * 32 + row) * 8 + (na & 7)));
  const float bv0 = (na < 1046) ? db1[na] : 0.f;
  const float bv1 = (na + 1 < 1046) ? db1[na + 1] : 0.f;
  int gen = 0;
  __syncthreads();   // weights staged
  // prologue: a0(0) = relu(hpart[0])   (a1(-1)=0 so M-term vanishes)
  {
    u32 pk = *(const u32*)(hpart + row * 1152 + na);
    float s0 = fmaxf(h2f((u16)(pk & 0xffff)), 0.f);
    float s1 = fmaxf(h2f((u16)(pk >> 16)), 0.f);
    st_act4(a0slot, (u32)f2h(s0) | ((u32)f2h(s1) << 16));
  }
  gbar(flags, bid, tid, ++gen);
#pragma unroll 1
  for (int t = 0; t < 512; ++t) {
    // hpart prefetch FIRST: in-order vmcnt retire -> never extends a drain.
    u32 hpk = 0;
    if (t < 511) hpk = *(const u32*)(hpart + (size_t)(t + 1) * 36864 + row * 1152 + na);
    // ---- phase 1: a1 = relu(a0 @ W1 + db1) ----
    float s0, s1;
    dec_mm(a0, wlds, red, tid, lm, lg, wv, e0, s0, s1);
    s0 = fmaxf(s0 + bv0, 0.f);
    s1 = fmaxf(s1 + bv1, 0.f);
    u32 opk = (u32)f2h(s0) | ((u32)f2h(s1) << 16);
    if (t == 511) {
      *(u32*)(a1buf + ((size_t)(t * 32 + row) * 1088 + na)) = opk;  // last step: log only
      break;
    }
    st_act4(a1slot, opk);
    gbar(flags, bid, tid, ++gen);
    // a1buf log AFTER the barrier: ack drains under phase-2's compute window (r12).
    *(u32*)(a1buf + ((size_t)(t * 32 + row) * 1088 + na)) = opk;
    // ---- phase 2: a0' = relu(a1 @ M + hpart[t+1]) ----
    dec_mm(a1, wlds + 2304 * 8, red, tid, lm, lg, wv, e0, s0, s1);
    s0 = fmaxf(s0 + h2f((u16)(hpk & 0xffff)), 0.f);
    s1 = fmaxf(s1 + h2f((u16)(hpk >> 16)), 0.f);
    st_act4(a0slot, (u32)f2h(s0) | ((u32)f2h(s1) << 16));
    gbar(flags, bid, tid, ++gen);
  }
}

// ---------------- finalize: dout[b][n][t] = ytmp[t*32+b][n] ----------------
__global__ __launch_bounds__(256) void finalize_kernel(const u16* __restrict__ ytmp,
                                                       float* __restrict__ dout) {
  __shared__ float tile[64][65];
  int b = blockIdx.z, n0 = blockIdx.x * 64, t0 = blockIdx.y * 64;
  for (int rep = 0; rep < 16; ++rep) {
    int e = rep * 256 + threadIdx.x;
    int tt = e >> 6, nn = e & 63;
    tile[tt][nn] = h2f(ytmp[(size_t)((t0 + tt) * 32 + b) * 1024 + n0 + nn]);
  }
  __syncthreads();
  for (int rep = 0; rep < 16; ++rep) {
    int e = rep * 256 + threadIdx.x;
    int nn = e >> 6, tt = e & 63;
    dout[((size_t)b * 1024 + n0 + nn) * 512 + t0 + tt] = tile[tt][nn];
  }
}

// ---------------- launch ----------------
extern "C" void kernel_launch(void* const* d_in, const int* in_sizes, int n_in,
                              void* d_out, int out_size, void* d_ws, size_t ws_size,
                              hipStream_t stream) {
  (void)in_sizes; (void)n_in; (void)out_size; (void)ws_size;
  const float* x   = (const float*)d_in[0];
  const float* ew0 = (const float*)d_in[1];
  const float* eb0 = (const float*)d_in[2];
  const float* ew1 = (const float*)d_in[3];
  const float* eb1 = (const float*)d_in[4];
  const float* ew2 = (const float*)d_in[5];
  const float* eb2 = (const float*)d_in[6];
  const float* dw0 = (const float*)d_in[7];
  const float* db0 = (const float*)d_in[8];
  const float* dw1 = (const float*)d_in[9];
  const float* db1 = (const float*)d_in[10];
  const float* dw2 = (const float*)d_in[11];
  const float* db2 = (const float*)d_in[12];

  char* ws = (char*)d_ws;
  u16* xT    = (u16*)(ws + 0);                      // 33.6MB; dead after encoder L0 -> reused as ytmp
  u16* ytmp  = (u16*)(ws + 0);
  u16* act2  = (u16*)(ws + 33619968ull);            // 25MB region (dead after hid GEMM):
  u16* A16   = (u16*)(ws + 33619968ull);            //   dw2 f16 [1152][1024] (aliases act2)
  u16* Mp    = (u16*)(ws + 33619968ull + 2359296ull);   // packed M (written after act2 dead)
  u16* hid   = (u16*)(ws + 58785792ull);
  u16* hpart = (u16*)(ws + 60882944ull);            // 16384*1152
  u16* We0p  = (u16*)(ws + 98631680ull);
  u16* We1p  = (u16*)(ws + 104398848ull);
  u16* We2p  = (u16*)(ws + 106561536ull);
  u16* Wh0p  = (u16*)(ws + 106659840ull);
  u16* Wd0p  = (u16*)(ws + 106807296ull);
  u16* Wd1p  = (u16*)(ws + 109461504ull);
  u16* Wd2p  = (u16*)(ws + 112115712ull);
  float* c2x = (float*)(ws + 114769920ull);
  u16* a0    = (u16*)(ws + 114774528ull);           // 144*32*8 f16, packed
  u16* a1    = (u16*)(ws + 114848256ull);
  int* flags = (int*)(ws + 114921984ull);           // 67*32 ints (never aliased)

  u16* act1  = (u16*)d_out;   // staged in d_out; dead after encoder L1
  u16* a1buf = (u16*)d_out;   // [16384][1088] f16 a1-log (cols>=1067 multiply zero W rows)
  float* dout = (float*)d_out;

  // fused prep: weight packs, xT t=-1 zero, c2x, flag zero, act zero (one launch)
  prep_kernel<<<dim3(4118), dim3(256), 0, stream>>>(
      ew0, ew1, ew2, dw0, dw1, dw2, db2,
      We0p, We1p, We2p, Wh0p, Wd0p, Wd1p, Wd2p, xT, c2x, flags, a0);

  transpose_kernel<<<dim3(16, 8, 32), dim3(256), 0, stream>>>(x, xT);

  // encoder (L0/L1: 128x128 tiles)
  gemm_kernel<1, 1, 1, 0, 0, 128><<<dim3(11, 128), dim3(256), 0, stream>>>(
      xT, 1024, We0p, 1408, eb0, 1387, ew0 + (size_t)2048 * 1387, 1387, nullptr, 0, act1, 1408, 2048);
  gemm_kernel<0, 1, 0, 0, 0, 128><<<dim3(6, 128), dim3(256), 0, stream>>>(
      act1, 1408, We1p, 768, eb1, 726, nullptr, 0, nullptr, 0, act2, 768, 1408);
  gemm_kernel<0, 2, 0, 0, 0, 64><<<dim3(1, 128), dim3(256), 0, stream>>>(
      act2, 768, We2p, 64, eb2, 64, nullptr, 0, nullptr, 0, hid, 64, 768);
  gemm_kernel<0, 0, 1, 1, 0, 64><<<dim3(18, 128), dim3(256), 0, stream>>>(
      hid, 64, Wh0p, 1152, db0, 1067, dw0 + (size_t)1088 * 1067, 1067, c2x, 1152, hpart, 1152, 64);

  // M = dw2 @ dw0[64:1088]  (act2 region dead after the hid gemm; A16/Mp live there)
  cvt_a_kernel<<<dim3(4608), dim3(256), 0, stream>>>(dw2, A16);
  gemm_kernel<0, 0, 0, 0, 1, 64><<<dim3(18, 9), dim3(256), 0, stream>>>(
      A16, 1024, Wd0p, 1152, nullptr, 0, nullptr, 0, nullptr, 0, Mp, 0, 1024);

  // sequential recurrence (r12-proven decoder)
  decoder_kernel<<<dim3(NWG), dim3(256), 0, stream>>>(Wd1p, Mp, hpart, db1, a0, a1, a1buf, flags);

  // deferred y = a1 @ W2 + db2  (128x128 tiles), then transpose into d_out
  gemm_kernel<0, 0, 0, 0, 0, 128><<<dim3(8, 128), dim3(256), 0, stream>>>(
      a1buf, 1088, Wd2p, 1152, db2, 1024, nullptr, 0, nullptr, 0, ytmp, 1024, 1088);
  finalize_kernel<<<dim3(16, 8, 32), dim3(256), 0, stream>>>(ytmp, dout);
}